// Round 5
// baseline (918.074 us; speedup 1.0000x reference)
//
#include <hip/hip_runtime.h>

#define BS   64
#define NQ   3000
#define NC   256
#define FH   100
#define FW   100
#define TOPK 1500
#define NT   512                 // threads per block (8 waves)
#define SB   25                  // score-chunk blocks per batch
#define RPB  (NQ / SB)           // 120 rows per block

// ---------------- fused: scores + (last block per batch) top-k/raster/emit --
__global__ __launch_bounds__(NT) void fused_kernel(const float4* __restrict__ coord,
                                                   const float4* __restrict__ cls,
                                                   const int* __restrict__ vfs,
                                                   float* __restrict__ scores,
                                                   int* __restrict__ done,
                                                   float* __restrict__ out) {
    __shared__ unsigned su[NQ];
    __shared__ int      hist[8][256];
    __shared__ unsigned cov[FH * 4];
    __shared__ int      eqlist[NQ];
    __shared__ int      wave_sum[4];
    __shared__ int      s_selbin, s_K, s_ecnt, s_old;

    const int blk  = blockIdx.x;       // 0 .. BS*SB-1
    const int b    = blk / SB;
    const int chnk = blk % SB;
    const int tid  = threadIdx.x;
    const int lane = tid & 63;
    const int wave = tid >> 6;

    // ---- phase 1: scores for this 120-row chunk (4 rows in flight per wave) ----
    const int rowbase = b * NQ + chnk * RPB;
    for (int r = wave * 4; r < RPB; r += 32) {           // starts mult of 4, r+4<=RPB
        const int row0 = rowbase + r;
        const float4* p = cls + (size_t)row0 * (NC / 4) + lane;
        float4 a = p[0], b4 = p[64], c = p[128], d = p[192];
        float m0 = fmaxf(fmaxf(a.x, a.y), fmaxf(a.z, a.w));
        float m1 = fmaxf(fmaxf(b4.x, b4.y), fmaxf(b4.z, b4.w));
        float m2 = fmaxf(fmaxf(c.x, c.y), fmaxf(c.z, c.w));
        float m3 = fmaxf(fmaxf(d.x, d.y), fmaxf(d.z, d.w));
#pragma unroll
        for (int off = 32; off > 0; off >>= 1) {
            m0 = fmaxf(m0, __shfl_xor(m0, off, 64));
            m1 = fmaxf(m1, __shfl_xor(m1, off, 64));
            m2 = fmaxf(m2, __shfl_xor(m2, off, 64));
            m3 = fmaxf(m3, __shfl_xor(m3, off, 64));
        }
        if (lane < 4) {
            float m = (lane == 0) ? m0 : (lane == 1) ? m1 : (lane == 2) ? m2 : m3;
            scores[row0 + lane] = m;
        }
    }

    // ---- release + arrive; last block of this batch takes over ----
    __threadfence();                        // make my score stores device-visible
    __syncthreads();
    if (tid == 0) s_old = atomicAdd(&done[b], 1);   // device-scope by default
    __syncthreads();
    if (s_old != SB - 1) return;
    __threadfence();                        // acquire: invalidate stale cache lines

    // ---- phase 2: top-k select + raster + emit for batch b (one block) ----
    for (int q = tid; q < NQ; q += NT)
        su[q] = __float_as_uint(scores[b * NQ + q]);
    for (int i = tid; i < FH * 4; i += NT) cov[i] = 0u;
    if (tid == 0) s_ecnt = 0;

    unsigned prefix = 0, pmask = 0;
    int K = TOPK;
#pragma unroll
    for (int p = 0; p < 4; ++p) {
        const int shift = 24 - 8 * p;
        for (int i = tid; i < 8 * 256; i += NT) ((int*)hist)[i] = 0;
        __syncthreads();
        for (int q = tid; q < NQ; q += NT) {
            unsigned u = su[q];
            if ((u & pmask) == prefix)
                atomicAdd(&hist[wave][(u >> shift) & 0xFF], 1);
        }
        __syncthreads();
        int x = 0, hx = 0, bin = 0;
        if (tid < 256) {
            bin = 255 - tid;
            hx = hist[0][bin] + hist[1][bin] + hist[2][bin] + hist[3][bin] +
                 hist[4][bin] + hist[5][bin] + hist[6][bin] + hist[7][bin];
            x = hx;
#pragma unroll
            for (int off = 1; off < 64; off <<= 1) {
                int y = __shfl_up(x, off, 64);
                if ((tid & 63) >= off) x += y;
            }
            if ((tid & 63) == 63) wave_sum[tid >> 6] = x;
        }
        __syncthreads();
        if (tid < 256) {
            int w = tid >> 6;
            for (int j = 0; j < w; ++j) x += wave_sum[j];
            int ge_incl = x;
            int ge_excl = x - hx;
            if (ge_incl >= K && ge_excl < K) { s_selbin = bin; s_K = K - ge_excl; }
        }
        __syncthreads();
        prefix |= ((unsigned)s_selbin) << shift;
        pmask  |= (0xFFu << shift);
        K = s_K;
        __syncthreads();
    }
    const unsigned v      = prefix;   // exact TOPK-th largest bits
    const int      e_take = K;        // ties taken (smallest index first)

    const float s0 = (float)vfs[2 * b];      // x scaled by vfs[:,0] (reference quirk)
    const float s1 = (float)vfs[2 * b + 1];  // y scaled by vfs[:,1]

    for (int q = tid; q < NQ; q += NT) {
        unsigned u = su[q];
        if (u > v) {
            float4 c4 = coord[(size_t)b * NQ + q];
            float x1 = c4.x - 0.5f * c4.z, y1 = c4.y - 0.5f * c4.w;
            float x2 = c4.x + 0.5f * c4.z, y2 = c4.y + 0.5f * c4.w;
            int lx = (int)floorf(x1 * s0), ly = (int)floorf(y1 * s1);
            int rx = (int)floorf(x2 * s0), ry = (int)floorf(y2 * s1);
            int h0 = ly > 0 ? ly : 0, h1 = ry < FH ? ry : FH;
            int w0 = lx > 0 ? lx : 0, w1 = rx < FW ? rx : FW;
            if (h0 < h1 && w0 < w1) {
                unsigned m[4];
#pragma unroll
                for (int j = 0; j < 4; ++j) {
                    int lo = w0 - 32 * j; lo = lo < 0 ? 0 : lo;
                    int hi = w1 - 32 * j; hi = hi > 32 ? 32 : hi;
                    unsigned mm = 0u;
                    if (hi > lo) {
                        unsigned top = (hi >= 32) ? 0xFFFFFFFFu : ((1u << hi) - 1u);
                        unsigned bot = (lo <= 0) ? 0u : ((1u << lo) - 1u);
                        mm = top & ~bot;
                    }
                    m[j] = mm;
                }
                for (int h = h0; h < h1; ++h)
#pragma unroll
                    for (int j = 0; j < 4; ++j)
                        if (m[j]) atomicOr(&cov[h * 4 + j], m[j]);
            }
        } else if (u == v) {
            int i = atomicAdd(&s_ecnt, 1);
            eqlist[i] = q;
        }
    }
    __syncthreads();

    const int E = s_ecnt;
    for (int i = tid; i < E; i += NT) {
        int q = eqlist[i];
        int r = 0;
        for (int j = 0; j < E; ++j) r += (eqlist[j] < q) ? 1 : 0;
        if (r < e_take) {
            float4 c4 = coord[(size_t)b * NQ + q];
            float x1 = c4.x - 0.5f * c4.z, y1 = c4.y - 0.5f * c4.w;
            float x2 = c4.x + 0.5f * c4.z, y2 = c4.y + 0.5f * c4.w;
            int lx = (int)floorf(x1 * s0), ly = (int)floorf(y1 * s1);
            int rx = (int)floorf(x2 * s0), ry = (int)floorf(y2 * s1);
            int h0 = ly > 0 ? ly : 0, h1 = ry < FH ? ry : FH;
            int w0 = lx > 0 ? lx : 0, w1 = rx < FW ? rx : FW;
            if (h0 < h1 && w0 < w1) {
                for (int h = h0; h < h1; ++h)
#pragma unroll
                    for (int j = 0; j < 4; ++j) {
                        int lo = w0 - 32 * j; lo = lo < 0 ? 0 : lo;
                        int hi = w1 - 32 * j; hi = hi > 32 ? 32 : hi;
                        if (hi > lo) {
                            unsigned top = (hi >= 32) ? 0xFFFFFFFFu : ((1u << hi) - 1u);
                            unsigned bot = (lo <= 0) ? 0u : ((1u << lo) - 1u);
                            atomicOr(&cov[h * 4 + j], top & ~bot);
                        }
                    }
            }
        }
    }
    __syncthreads();

    const int iv0 = vfs[2 * b], iv1 = vfs[2 * b + 1];
    for (int idx = tid; idx < FH * FW; idx += NT) {
        int h = idx / FW;
        int w = idx - h * FW;
        bool covered = (cov[h * 4 + (w >> 5)] >> (w & 31)) & 1u;
        bool pad = (h >= iv0) || (w >= iv1);
        out[(size_t)b * (FH * FW) + idx] = (covered && !pad) ? 0.0f : -1e20f;
    }
}

extern "C" void kernel_launch(void* const* d_in, const int* in_sizes, int n_in,
                              void* d_out, int out_size, void* d_ws, size_t ws_size,
                              hipStream_t stream) {
    const float4* coord = (const float4*)d_in[0];  // (BS, NQ, 4) f32
    const float4* cls   = (const float4*)d_in[1];  // (BS, NQ, NC) f32
    const int*    vfs   = (const int*)d_in[2];     // (BS, 2) i32
    // d_in[3] (padding_mask) ignored — recomputed from vfs.
    float* scores = (float*)d_ws;                              // BS*NQ floats
    int*   done   = (int*)((char*)d_ws + (size_t)BS * NQ * 4); // BS counters
    float* out    = (float*)d_out;

    // d_ws is re-poisoned 0xAA before every launch: zero the counters.
    hipMemsetAsync(done, 0, BS * sizeof(int), stream);
    fused_kernel<<<BS * SB, NT, 0, stream>>>(coord, cls, vfs, scores, done, out);
}

// Round 6
// 321.452 us; speedup vs baseline: 2.8560x; 2.8560x over previous
//
#include <hip/hip_runtime.h>

#define BS   64
#define NQ   3000
#define NC   256
#define FH   100
#define FW   100
#define TOPK 1500

// ---------------- Kernel A: scores[b,q] = max_c class[b,q,c] ----------------
// One row (64 float4) per wave-instruction; 8 rows per wave in flight ->
// 8 independent coalesced 1KB loads outstanding per wave. 32 rows/block.
__global__ __launch_bounds__(256) void scores_kernel(const float4* __restrict__ cls,
                                                     float* __restrict__ scores) {
    const int tid  = threadIdx.x;
    const int lane = tid & 63;
    const int wave = tid >> 6;
    const int row0 = blockIdx.x * 32 + wave * 8;   // grid exact: 48000/32 blocks
    const float4* p = cls + (size_t)row0 * (NC / 4) + lane;
    float m[8];
#pragma unroll
    for (int r = 0; r < 8; ++r) {
        float4 v = p[r * 64];                      // row r, float4 #lane
        m[r] = fmaxf(fmaxf(v.x, v.y), fmaxf(v.z, v.w));
    }
#pragma unroll
    for (int off = 32; off > 0; off >>= 1) {
#pragma unroll
        for (int r = 0; r < 8; ++r)
            m[r] = fmaxf(m[r], __shfl_xor(m[r], off, 64));
    }
    if (lane < 8) {
        float mv = m[0];
#pragma unroll
        for (int r = 1; r < 8; ++r) mv = (lane == r) ? m[r] : mv;
        scores[row0 + lane] = mv;
    }
}

// ---------------- Kernel B: per-batch top-k select + raster + mask ----------
#define NTM 512  // 8 waves

__global__ __launch_bounds__(NTM) void mask_kernel(const float4* __restrict__ coord,
                                                   const int* __restrict__ vfs,
                                                   const float* __restrict__ scores,
                                                   float* __restrict__ out) {
    __shared__ unsigned su[NQ];        // score bits (positive: uint order == float order)
    __shared__ int      hist[8][256];  // per-wave histograms
    __shared__ unsigned cov[FH * 4];   // 100 rows x 128-bit coverage
    __shared__ int      eqlist[NQ];    // ties at v (worst case all)
    __shared__ int      wave_sum[4];
    __shared__ int      s_selbin, s_K, s_ecnt;

    const int b   = blockIdx.x;
    const int tid = threadIdx.x;
    const int wid = tid >> 6;

    for (int q = tid; q < NQ; q += NTM)
        su[q] = __float_as_uint(scores[b * NQ + q]);
    for (int i = tid; i < FH * 4; i += NTM) cov[i] = 0u;
    if (tid == 0) s_ecnt = 0;

    // ---- byte-wise radix descent with parallel suffix-scan bin select ----
    unsigned prefix = 0, pmask = 0;
    int K = TOPK;
#pragma unroll
    for (int p = 0; p < 4; ++p) {
        const int shift = 24 - 8 * p;
        for (int i = tid; i < 8 * 256; i += NTM) ((int*)hist)[i] = 0;
        __syncthreads();
        for (int q = tid; q < NQ; q += NTM) {
            unsigned u = su[q];
            if ((u & pmask) == prefix)
                atomicAdd(&hist[wid][(u >> shift) & 0xFF], 1);
        }
        __syncthreads();
        int x = 0, hx = 0, bin = 0;
        if (tid < 256) {
            bin = 255 - tid;
            hx = hist[0][bin] + hist[1][bin] + hist[2][bin] + hist[3][bin] +
                 hist[4][bin] + hist[5][bin] + hist[6][bin] + hist[7][bin];
            x = hx;
#pragma unroll
            for (int off = 1; off < 64; off <<= 1) {
                int y = __shfl_up(x, off, 64);
                if ((tid & 63) >= off) x += y;
            }
            if ((tid & 63) == 63) wave_sum[tid >> 6] = x;
        }
        __syncthreads();
        if (tid < 256) {
            int w = tid >> 6;
            for (int j = 0; j < w; ++j) x += wave_sum[j];
            int ge_incl = x;          // prefix-matching scores with byte >= bin
            int ge_excl = x - hx;     // with byte > bin
            if (ge_incl >= K && ge_excl < K) { s_selbin = bin; s_K = K - ge_excl; }
        }
        __syncthreads();
        prefix |= ((unsigned)s_selbin) << shift;
        pmask  |= (0xFFu << shift);
        K = s_K;
        __syncthreads();
    }
    const unsigned v      = prefix;   // exact bits of TOPK-th largest
    const int      e_take = K;        // ties taken (smallest index first)

    const float s0 = (float)vfs[2 * b];      // x scaled by vfs[:,0] (reference quirk)
    const float s1 = (float)vfs[2 * b + 1];  // y scaled by vfs[:,1]

    // ---- selection + raster (LDS atomicOr; conflicts measured negligible) ----
    for (int q = tid; q < NQ; q += NTM) {
        unsigned u = su[q];
        if (u > v) {
            float4 c4 = coord[(size_t)b * NQ + q];
            float x1 = c4.x - 0.5f * c4.z, y1 = c4.y - 0.5f * c4.w;
            float x2 = c4.x + 0.5f * c4.z, y2 = c4.y + 0.5f * c4.w;
            int lx = (int)floorf(x1 * s0), ly = (int)floorf(y1 * s1);
            int rx = (int)floorf(x2 * s0), ry = (int)floorf(y2 * s1);
            int h0 = ly > 0 ? ly : 0, h1 = ry < FH ? ry : FH;
            int w0 = lx > 0 ? lx : 0, w1 = rx < FW ? rx : FW;
            if (h0 < h1 && w0 < w1) {
                unsigned m[4];
#pragma unroll
                for (int j = 0; j < 4; ++j) {
                    int lo = w0 - 32 * j; lo = lo < 0 ? 0 : lo;
                    int hi = w1 - 32 * j; hi = hi > 32 ? 32 : hi;
                    unsigned mm = 0u;
                    if (hi > lo) {
                        unsigned top = (hi >= 32) ? 0xFFFFFFFFu : ((1u << hi) - 1u);
                        unsigned bot = (lo <= 0) ? 0u : ((1u << lo) - 1u);
                        mm = top & ~bot;
                    }
                    m[j] = mm;
                }
                for (int h = h0; h < h1; ++h)
#pragma unroll
                    for (int j = 0; j < 4; ++j)
                        if (m[j]) atomicOr(&cov[h * 4 + j], m[j]);
            }
        } else if (u == v) {
            int i = atomicAdd(&s_ecnt, 1);
            eqlist[i] = q;
        }
    }
    __syncthreads();

    // ---- stable tie-break: take e_take smallest-index ties ----
    const int E = s_ecnt;
    for (int i = tid; i < E; i += NTM) {
        int q = eqlist[i];
        int r = 0;
        for (int j = 0; j < E; ++j) r += (eqlist[j] < q) ? 1 : 0;
        if (r < e_take) {
            float4 c4 = coord[(size_t)b * NQ + q];
            float x1 = c4.x - 0.5f * c4.z, y1 = c4.y - 0.5f * c4.w;
            float x2 = c4.x + 0.5f * c4.z, y2 = c4.y + 0.5f * c4.w;
            int lx = (int)floorf(x1 * s0), ly = (int)floorf(y1 * s1);
            int rx = (int)floorf(x2 * s0), ry = (int)floorf(y2 * s1);
            int h0 = ly > 0 ? ly : 0, h1 = ry < FH ? ry : FH;
            int w0 = lx > 0 ? lx : 0, w1 = rx < FW ? rx : FW;
            if (h0 < h1 && w0 < w1) {
                for (int h = h0; h < h1; ++h)
#pragma unroll
                    for (int j = 0; j < 4; ++j) {
                        int lo = w0 - 32 * j; lo = lo < 0 ? 0 : lo;
                        int hi = w1 - 32 * j; hi = hi > 32 ? 32 : hi;
                        if (hi > lo) {
                            unsigned top = (hi >= 32) ? 0xFFFFFFFFu : ((1u << hi) - 1u);
                            unsigned bot = (lo <= 0) ? 0u : ((1u << lo) - 1u);
                            atomicOr(&cov[h * 4 + j], top & ~bot);
                        }
                    }
            }
        }
    }
    __syncthreads();

    // ---- emit mask fused with padding (recomputed from vfs) ----
    const int iv0 = vfs[2 * b], iv1 = vfs[2 * b + 1];
    for (int idx = tid; idx < FH * FW; idx += NTM) {
        int h = idx / FW;
        int w = idx - h * FW;
        bool covered = (cov[h * 4 + (w >> 5)] >> (w & 31)) & 1u;
        bool pad = (h >= iv0) || (w >= iv1);
        out[(size_t)b * (FH * FW) + idx] = (covered && !pad) ? 0.0f : -1e20f;
    }
}

extern "C" void kernel_launch(void* const* d_in, const int* in_sizes, int n_in,
                              void* d_out, int out_size, void* d_ws, size_t ws_size,
                              hipStream_t stream) {
    const float4* coord = (const float4*)d_in[0];  // (BS, NQ, 4) f32
    const float*  cls   = (const float*)d_in[1];   // (BS, NQ, NC) f32
    const int*    vfs   = (const int*)d_in[2];     // (BS, 2) i32
    // d_in[3] (padding_mask) ignored — recomputed from vfs.
    float* scores = (float*)d_ws;                  // BS*NQ floats
    float* out    = (float*)d_out;

    scores_kernel<<<(BS * NQ) / 32, 256, 0, stream>>>((const float4*)cls, scores);
    mask_kernel<<<BS, NTM, 0, stream>>>(coord, vfs, scores, out);
}